// Round 15
// baseline (349.364 us; speedup 1.0000x reference)
//
#include <hip/hip_runtime.h>
#include <hip/hip_bf16.h>
#include <cstdint>
#include <cstddef>

#define BB 32
#define LL 2048
#define DD 1024
#define HH 16
#define HDIM 64
#define NL 4
#define NCHUNK 16      // chunks per sequence
#define CHUNK 128      // tokens per chunk (grid 512 -> 2 blocks/CU co-resident)
#define NEGINF -1e30f
#define KSP 32         // output K-splits for epilogue GEMV partials (512 blocks)
#define KL  32         // 1024 / KSP

typedef __attribute__((ext_vector_type(8))) short bf16x8;
typedef __attribute__((ext_vector_type(4))) float f32x4;

__device__ __forceinline__ unsigned short f2b(float x) {
    union { float f; unsigned int u; } v; v.f = x;
    unsigned int r = (v.u + 0x7FFFu + ((v.u >> 16) & 1u)) >> 16;
    return (unsigned short)r;
}
__device__ __forceinline__ float b2f(unsigned short u) {
    union { unsigned int u; float f; } v; v.u = ((unsigned int)u) << 16;
    return v.f;
}

// ---------------- split-K GEMV partials: part[ks][b][c] = X[b, e0:e0+32] @ W[e0:e0+32, c]
// SRC 2: X = bias + sum_{j2<KSP} parts_in    (combine pv partials)
// SRC 3: X = sum_c8 wgt[b][c8]*ctx16[...]    (softmax chunk combine; head = ct)
// grid 512 (= 16 ct x 32 ks) x 512 threads -> 2 blocks/CU, K-chain 32.
template<int SRC>
__global__ __launch_bounds__(512) void k_gemv(
        const float* __restrict__ parts_in, const float* __restrict__ bias_in,
        const unsigned short* __restrict__ ctx16, const float* __restrict__ m_p,
        const float* __restrict__ s_p,
        const float* __restrict__ W, float* __restrict__ outp) {
    int bid = blockIdx.x, tid = threadIdx.x;
    int ct = bid & 15, ks = bid >> 4;   // ks 0..31
    int e0 = ks * KL;
    __shared__ float Xs[BB][KL];
    __shared__ float wgtS[BB][NCHUNK];
    __shared__ float mgS[BB], SgS[BB];
    if (SRC == 3) {
        if (tid < BB) {
            int b = tid; float m = NEGINF;
            for (int c8 = 0; c8 < NCHUNK; ++c8)
                m = fmaxf(m, m_p[(b * NCHUNK + c8) * HH + ct]);
            float S = 0.f;
            for (int c8 = 0; c8 < NCHUNK; ++c8)
                S += s_p[(b * NCHUNK + c8) * HH + ct] *
                     __expf(m_p[(b * NCHUNK + c8) * HH + ct] - m);
            mgS[b] = m; SgS[b] = S;
        }
        __syncthreads();
        {
            int b = tid >> 4, c8 = tid & 15;   // 512 threads = 32 x 16
            wgtS[b][c8] = __expf(m_p[(b * NCHUNK + c8) * HH + ct] - mgS[b]) / SgS[b];
        }
        __syncthreads();
    }
    // stage Xs[32][32]: 256 active threads, thread = (b, kq of 4 elems)
    if (tid < 256) {
        int b = tid >> 3, kq = tid & 7;
        int k = kq * 4;
        float x0, x1, x2, x3;
        if (SRC == 2) {
            const float4 bi = *(const float4*)&bias_in[e0 + k];
            x0 = bi.x; x1 = bi.y; x2 = bi.z; x3 = bi.w;
#pragma unroll
            for (int j2 = 0; j2 < KSP; ++j2) {
                const float4 v = *(const float4*)&parts_in[((size_t)(j2 * BB) + b) * DD + e0 + k];
                x0 += v.x; x1 += v.y; x2 += v.z; x3 += v.w;
            }
        } else {
            x0 = x1 = x2 = x3 = 0.f;
#pragma unroll
            for (int c8 = 0; c8 < NCHUNK; ++c8) {
                const ushort4 u = *(const ushort4*)&ctx16[(((size_t)(b * NCHUNK + c8)) * HH + ct) * DD + e0 + k];
                float wq = wgtS[b][c8];
                x0 += wq * b2f(u.x); x1 += wq * b2f(u.y);
                x2 += wq * b2f(u.z); x3 += wq * b2f(u.w);
            }
        }
        float4 xv = {x0, x1, x2, x3};
        *(float4*)&Xs[b][k] = xv;
    }
    __syncthreads();
    int col = tid & 63, bg = tid >> 6;   // bg 0..7, 4 b's each
    int c = ct * 64 + col;
    float acc[4] = {0.f, 0.f, 0.f, 0.f};
    for (int k = 0; k < KL; k += 4) {
        float w0 = W[(size_t)(e0 + k) * DD + c];
        float w1 = W[(size_t)(e0 + k + 1) * DD + c];
        float w2 = W[(size_t)(e0 + k + 2) * DD + c];
        float w3 = W[(size_t)(e0 + k + 3) * DD + c];
#pragma unroll
        for (int bb = 0; bb < 4; ++bb) {
            const float4 xv = *(const float4*)&Xs[bg * 4 + bb][k];
            acc[bb] += xv.x * w0 + xv.y * w1 + xv.z * w2 + xv.w * w3;
        }
    }
#pragma unroll
    for (int bb = 0; bb < 4; ++bb)
        outp[((size_t)(ks * BB) + bg * 4 + bb) * DD + c] = acc[bb];
}

// ---------------- last layer: combine op partials (KSP) + bo + LN -> out (32 x 1024)
__global__ __launch_bounds__(1024) void k_statsF(const float* __restrict__ parts,
        const float* __restrict__ bo, const float* __restrict__ gamma,
        const float* __restrict__ beta, float* __restrict__ outp) {
    int b = blockIdx.x, c = threadIdx.x;
    float v = bo[c];
#pragma unroll
    for (int ks = 0; ks < KSP; ++ks)
        v += parts[((size_t)(ks * BB) + b) * DD + c];
    float s1 = v, s2 = v * v;
#pragma unroll
    for (int off = 32; off; off >>= 1) {
        s1 += __shfl_xor(s1, off);
        s2 += __shfl_xor(s2, off);
    }
    __shared__ float r1[16], r2[16];
    __shared__ float smu, srs;
    int w = c >> 6;
    if ((c & 63) == 0) { r1[w] = s1; r2[w] = s2; }
    __syncthreads();
    if (c == 0) {
        float a = 0.f, q = 0.f;
#pragma unroll
        for (int i = 0; i < 16; ++i) { a += r1[i]; q += r2[i]; }
        float mu = a / (float)DD, var = q / (float)DD - mu * mu;
        smu = mu; srs = rsqrtf(var + 1e-5f);
    }
    __syncthreads();
    outp[(size_t)b * DD + c] = (v - smu) * srs * gamma[c] + beta[c];
}

// ---------------- fused: op-combine (KSP) + bo -> LN -> @Wq + bq -> qh rows
__global__ __launch_bounds__(512) void k_qnext(const float* __restrict__ op,
        const float* __restrict__ bo, const float* __restrict__ gamma,
        const float* __restrict__ beta, const float* __restrict__ Wq,
        const float* __restrict__ bq, float* __restrict__ qh) {
    int bid = blockIdx.x, tid = threadIdx.x;
    int ct = bid & 15, bp = bid >> 4;
    int b0 = bp * 2;
    __shared__ float Xr[2][DD];
    __shared__ float pr[8][2][64];
    __shared__ float r1[8], r2[8];
    __shared__ float smu[2], srs[2];
    {
        int bb = tid >> 8, c4 = tid & 255;
        int c = c4 * 4;
        float4 x = *(const float4*)&bo[c];
#pragma unroll
        for (int ks = 0; ks < KSP; ++ks) {
            const float4 v = *(const float4*)&op[((size_t)(ks * BB) + b0 + bb) * DD + c];
            x.x += v.x; x.y += v.y; x.z += v.z; x.w += v.w;
        }
        *(float4*)&Xr[bb][c] = x;
    }
    __syncthreads();
    {
        int bb = tid >> 8, l = tid & 255;
        const float4 x = *(const float4*)&Xr[bb][l * 4];
        float s1 = x.x + x.y + x.z + x.w;
        float s2 = x.x * x.x + x.y * x.y + x.z * x.z + x.w * x.w;
#pragma unroll
        for (int off = 32; off; off >>= 1) {
            s1 += __shfl_xor(s1, off);
            s2 += __shfl_xor(s2, off);
        }
        int w = tid >> 6;
        if ((tid & 63) == 0) { r1[w] = s1; r2[w] = s2; }
    }
    __syncthreads();
    if (tid < 2) {
        float a = r1[tid * 4] + r1[tid * 4 + 1] + r1[tid * 4 + 2] + r1[tid * 4 + 3];
        float q = r2[tid * 4] + r2[tid * 4 + 1] + r2[tid * 4 + 2] + r2[tid * 4 + 3];
        float mu = a / (float)DD, var = q / (float)DD - mu * mu;
        smu[tid] = mu; srs[tid] = rsqrtf(var + 1e-5f);
    }
    __syncthreads();
    {
        int c = tid & 63, ks8 = tid >> 6;
        float mu0 = smu[0], rs0 = srs[0], mu1 = smu[1], rs1 = srs[1];
        float acc0 = 0.f, acc1 = 0.f;
        int k0 = ks8 * 128;
        for (int k = k0; k < k0 + 128; ++k) {
            float g = gamma[k], be = beta[k];
            float w = Wq[(size_t)k * DD + ct * 64 + c];
            float x0 = (Xr[0][k] - mu0) * rs0 * g + be;
            float x1 = (Xr[1][k] - mu1) * rs1 * g + be;
            acc0 += x0 * w;
            acc1 += x1 * w;
        }
        pr[ks8][0][c] = acc0;
        pr[ks8][1][c] = acc1;
    }
    __syncthreads();
    if (tid < 128) {
        int bb = tid >> 6, c = tid & 63;
        float q = bq[ct * 64 + c];
#pragma unroll
        for (int j = 0; j < 8; ++j) q += pr[j][bb][c];
        qh[((size_t)(b0 + bb)) * DD + ct * 64 + c] = q;
    }
}

// ---------------- prologue: qh[0] = qt @ Wq0 + bq0 (one row; all b identical)
__global__ __launch_bounds__(256) void k_q0(const float* __restrict__ qt,
        const float* __restrict__ Wq, const float* __restrict__ bq,
        float* __restrict__ qh) {
    int ct = blockIdx.x, tid = threadIdx.x;
    __shared__ float pr[4][64];
    int c = tid & 63, ks4 = tid >> 6;
    float acc = 0.f;
    int k0 = ks4 * 256;
    for (int k = k0; k < k0 + 256; ++k)
        acc += qt[k] * Wq[(size_t)k * DD + ct * 64 + c];
    pr[ks4][c] = acc;
    __syncthreads();
    if (tid < 64) {
        float q = bq[ct * 64 + tid];
#pragma unroll
        for (int j = 0; j < 4; ++j) q += pr[j][tid];
        qh[ct * 64 + tid] = q;
    }
}

// ---------------- wk[b,h,e] = Wk[e, h*64:+64] . qh[b|0, h*64:+64] (bf16) + sbuf
template<int BCAST>
__global__ __launch_bounds__(256) void k_wk(const float* __restrict__ qh,
        const float* __restrict__ Wk, const float* __restrict__ bk,
        unsigned short* __restrict__ wk16, float* __restrict__ sb) {
    int h = blockIdx.x >> 4, et = blockIdx.x & 15;
    int tid = threadIdx.x;
    __shared__ float qs[BB][HDIM + 1];
    for (int i = tid; i < BB * HDIM; i += 256) {
        int bb = i >> 6, d = i & 63;
        qs[bb][d] = qh[((size_t)(BCAST ? 0 : bb)) * DD + h * HDIM + d];
    }
    __syncthreads();
    int b = tid & 31, eo = tid >> 5;   // eo: 0..7
    for (int k = 0; k < 8; ++k) {
        int e = et * 64 + eo * 8 + k;
        const float* wrow = Wk + (size_t)e * DD + h * HDIM;
        float acc = 0.f;
#pragma unroll
        for (int d = 0; d < HDIM; ++d) acc += qs[b][d] * wrow[d];
        wk16[((size_t)(b * HH + h)) * DD + e] = f2b(acc);
    }
    if (et == 0 && tid < BB) {
        float acc = 0.f;
#pragma unroll
        for (int d = 0; d < HDIM; ++d) acc += qs[tid][d] * bk[h * HDIM + d];
        sb[tid * HH + h] = acc;
    }
}

// ---------------- main streaming attention pass (partial per (b, chunk)) — R14
// CHUNK=128, grid 512 -> 2 blocks/CU (76 KB LDS, 8 waves, <=128 VGPR).
// MODE 0: fp32 reads. MODE 1: fp32 reads + bf16 cache write. MODE 2: bf16 cache reads.
template<int MODE>
__global__ __launch_bounds__(512, 4) void k_attn(const float* __restrict__ toks,
        unsigned short* __restrict__ tcache,
        const int* __restrict__ lens, const unsigned short* __restrict__ wk16,
        const float* __restrict__ sb, unsigned short* __restrict__ ctx16,
        float* __restrict__ m_p, float* __restrict__ s_p) {
    int b = blockIdx.x >> 4, chunk = blockIdx.x & 15;
    int tid = threadIdx.x, lane = tid & 63, w = tid >> 6;   // w: 0..7
    int len = lens[b];
    int base = chunk * CHUNK;
    int pidx = (b * NCHUNK + chunk) * HH;
    if (base >= len) {
        if (tid < HH) { m_p[pidx + tid] = NEGINF; s_p[pidx + tid] = 0.f; }
        return;
    }
    int nv = min(CHUNK, len - base);
    int ng = (nv + 31) >> 5;

    __shared__ __align__(16) unsigned short Tr[32][1032];   // [t][e] bf16, 66.0 KB
    __shared__ unsigned short SredH[8][HH][34];             // bf16 partials, 8.7 KB
    __shared__ unsigned short Pt[HH][40];
    __shared__ float sm_m[HH], sm_s[HH], sm_c[HH];

    if (tid < HH) { sm_m[tid] = NEGINF; sm_s[tid] = 0.f; }

    int hq = lane & 15, qg = lane >> 4;
    const unsigned short* wkb = wk16 + ((size_t)(b * HH + hq)) * DD + w * 128 + 8 * qg;
    bf16x8 afr0 = *(const bf16x8*)(wkb);
    bf16x8 afr1 = *(const bf16x8*)(wkb + 32);
    bf16x8 afr2 = *(const bf16x8*)(wkb + 64);
    bf16x8 afr3 = *(const bf16x8*)(wkb + 96);
    f32x4 zer = {0.f, 0.f, 0.f, 0.f};
    f32x4 ctxacc[8] = {zer, zer, zer, zer, zer, zer, zer, zer};
    float sbh = sb[b * HH + (tid >> 5)];
    int st = tid >> 6;           // staging token = wave id (0..7)
    int se = lane * 16;          // staging e offset
    const size_t rowbase = (size_t)(b * LL + base);
    __syncthreads();

    for (int g = 0; g < ng; ++g) {
        int t0 = g * 32;
        if (MODE == 2) {
            const unsigned short* s0p = tcache + (rowbase + t0) * DD + se;
#pragma unroll
            for (int p = 0; p < 4; ++p) {
                const unsigned short* sp = s0p + (size_t)(p * 8 + st) * DD;
                *(bf16x8*)&Tr[p * 8 + st][se]     = *(const bf16x8*)sp;
                *(bf16x8*)&Tr[p * 8 + st][se + 8] = *(const bf16x8*)(sp + 8);
            }
        } else {
            const float* s0p = toks + (rowbase + t0) * DD + se;
#pragma unroll
            for (int p = 0; p < 4; ++p) {
                const float* sp = s0p + (size_t)(p * 8 + st) * DD;
                float4 a0 = *(const float4*)sp;
                float4 a1 = *(const float4*)(sp + 4);
                float4 a2 = *(const float4*)(sp + 8);
                float4 a3 = *(const float4*)(sp + 12);
                bf16x8 v0, v1;
                v0[0] = f2b(a0.x); v0[1] = f2b(a0.y); v0[2] = f2b(a0.z); v0[3] = f2b(a0.w);
                v0[4] = f2b(a1.x); v0[5] = f2b(a1.y); v0[6] = f2b(a1.z); v0[7] = f2b(a1.w);
                v1[0] = f2b(a2.x); v1[1] = f2b(a2.y); v1[2] = f2b(a2.z); v1[3] = f2b(a2.w);
                v1[4] = f2b(a3.x); v1[5] = f2b(a3.y); v1[6] = f2b(a3.z); v1[7] = f2b(a3.w);
                *(bf16x8*)&Tr[p * 8 + st][se]     = v0;
                *(bf16x8*)&Tr[p * 8 + st][se + 8] = v1;
                if (MODE == 1) {
                    unsigned short* cp = tcache + (rowbase + t0 + p * 8 + st) * DD + se;
                    *(bf16x8*)cp = v0;
                    *(bf16x8*)(cp + 8) = v1;
                }
            }
        }
        __syncthreads();
        f32x4 s0 = zer, s1 = zer;
        {
            int eb = w * 128 + 8 * qg;
            s0 = __builtin_amdgcn_mfma_f32_16x16x32_bf16(afr0, *(const bf16x8*)&Tr[hq][eb], s0, 0, 0, 0);
            s0 = __builtin_amdgcn_mfma_f32_16x16x32_bf16(afr1, *(const bf16x8*)&Tr[hq][eb + 32], s0, 0, 0, 0);
            s0 = __builtin_amdgcn_mfma_f32_16x16x32_bf16(afr2, *(const bf16x8*)&Tr[hq][eb + 64], s0, 0, 0, 0);
            s0 = __builtin_amdgcn_mfma_f32_16x16x32_bf16(afr3, *(const bf16x8*)&Tr[hq][eb + 96], s0, 0, 0, 0);
            s1 = __builtin_amdgcn_mfma_f32_16x16x32_bf16(afr0, *(const bf16x8*)&Tr[16 + hq][eb], s1, 0, 0, 0);
            s1 = __builtin_amdgcn_mfma_f32_16x16x32_bf16(afr1, *(const bf16x8*)&Tr[16 + hq][eb + 32], s1, 0, 0, 0);
            s1 = __builtin_amdgcn_mfma_f32_16x16x32_bf16(afr2, *(const bf16x8*)&Tr[16 + hq][eb + 64], s1, 0, 0, 0);
            s1 = __builtin_amdgcn_mfma_f32_16x16x32_bf16(afr3, *(const bf16x8*)&Tr[16 + hq][eb + 96], s1, 0, 0, 0);
        }
#pragma unroll
        for (int r = 0; r < 4; ++r) {
            SredH[w][qg * 4 + r][hq] = f2b(s0[r]);
            SredH[w][qg * 4 + r][16 + hq] = f2b(s1[r]);
        }
        __syncthreads();
        {
            int h = tid >> 5, t = tid & 31;
            float s = 0.f;
#pragma unroll
            for (int ww = 0; ww < 8; ++ww) s += b2f(SredH[ww][h][t]);
            s = (s + sbh) * 0.125f;
            bool valid = (t0 + t) < nv;
            if (!valid) s = NEGINF;
            float tm = s;
#pragma unroll
            for (int off = 16; off; off >>= 1) tm = fmaxf(tm, __shfl_xor(tm, off, 32));
            float oldm = sm_m[h];
            float newm = fmaxf(oldm, tm);
            float pv = valid ? __expf(s - newm) : 0.f;
            float ps = pv;
#pragma unroll
            for (int off = 16; off; off >>= 1) ps += __shfl_xor(ps, off, 32);
            if (t == 0) {
                float corr = __expf(oldm - newm);
                sm_c[h] = corr;
                sm_m[h] = newm;
                sm_s[h] = sm_s[h] * corr + ps;
            }
            Pt[h][t] = f2b(pv);
        }
        __syncthreads();
        {
            float cr[4];
#pragma unroll
            for (int r = 0; r < 4; ++r) cr[r] = sm_c[qg * 4 + r];
            bf16x8 pafr;
            ushort4 pa0 = *(const ushort4*)&Pt[hq][8 * qg];
            ushort4 pa1 = *(const ushort4*)&Pt[hq][8 * qg + 4];
            pafr[0] = pa0.x; pafr[1] = pa0.y; pafr[2] = pa0.z; pafr[3] = pa0.w;
            pafr[4] = pa1.x; pafr[5] = pa1.y; pafr[6] = pa1.z; pafr[7] = pa1.w;
#pragma unroll
            for (int et = 0; et < 8; ++et) {
#pragma unroll
                for (int r = 0; r < 4; ++r) ctxacc[et][r] *= cr[r];
                bf16x8 bfr;
                int ec = w * 128 + et * 16 + hq;
#pragma unroll
                for (int i = 0; i < 8; ++i) bfr[i] = (short)Tr[8 * qg + i][ec];
                ctxacc[et] = __builtin_amdgcn_mfma_f32_16x16x32_bf16(pafr, bfr, ctxacc[et], 0, 0, 0);
            }
        }
        __syncthreads();
    }
    if (tid < HH) { m_p[pidx + tid] = sm_m[tid]; s_p[pidx + tid] = sm_s[tid]; }
#pragma unroll
    for (int et = 0; et < 8; ++et)
#pragma unroll
        for (int r = 0; r < 4; ++r) {
            int h = qg * 4 + r, e = w * 128 + et * 16 + hq;
            ctx16[((size_t)pidx + h) * DD + e] = f2b(ctxacc[et][r]);
        }
}

extern "C" void kernel_launch(void* const* d_in, const int* in_sizes, int n_in,
                              void* d_out, int out_size, void* d_ws, size_t ws_size,
                              hipStream_t stream) {
    const float* toks  = (const float*)d_in[0];
    const int*   lens  = (const int*)d_in[1];
    const float* qt    = (const float*)d_in[2];
    const float* Wq    = (const float*)d_in[3];
    const float* bq    = (const float*)d_in[4];
    const float* Wk    = (const float*)d_in[5];
    const float* bk    = (const float*)d_in[6];
    const float* Wv    = (const float*)d_in[7];
    const float* bv    = (const float*)d_in[8];
    const float* Wo    = (const float*)d_in[9];
    const float* bo    = (const float*)d_in[10];
    const float* gamma = (const float*)d_in[11];
    const float* beta  = (const float*)d_in[12];
    float* out = (float*)d_out;
    float* ws  = (float*)d_ws;

    // ws layout (float offsets)
    unsigned short* ctx16 = (unsigned short*)ws;   // 32*16*16*1024 u16 = 4194304 f
    float* m_p   = ws + 4194304;             // 8192
    float* s_p   = ws + 4202496;             // 8192
    float* pvp   = ws + 4210688;             // 1048576 (32 partials)
    float* op    = ws + 5259264;             // 1048576 (32 partials)
    float* qh    = ws + 6307840;             // 32768
    float* sbuf  = ws + 6340608;             // 512
    unsigned short* wk16 = (unsigned short*)(ws + 6341120);  // 524288 u16
    const size_t base_floats = 6603264;
    unsigned short* tcache = (unsigned short*)(ws + base_floats);
    const size_t need_cache = base_floats * 4 + (size_t)BB * LL * DD * 2;
    const bool use_cache = (ws_size >= need_cache);

    // prologue: qh row 0 = qt @ Wq0 + bq0; wk layer 0 writes ALL rows
    k_q0<<<16, 256, 0, stream>>>(qt, Wq, bq, qh);
    k_wk<1><<<256, 256, 0, stream>>>(qh, Wk, bk, wk16, sbuf);

    for (int i = 0; i < NL; ++i) {
        if (use_cache) {
            if (i == 0)
                k_attn<1><<<512, 512, 0, stream>>>(toks, tcache, lens, wk16,
                        sbuf, ctx16, m_p, s_p);
            else
                k_attn<2><<<512, 512, 0, stream>>>(toks, tcache, lens, wk16,
                        sbuf, ctx16, m_p, s_p);
        } else {
            k_attn<0><<<512, 512, 0, stream>>>(toks, tcache, lens, wk16,
                    sbuf, ctx16, m_p, s_p);
        }
        const float* Wv_i = Wv + (size_t)i * DD * DD;
        const float* Wo_i = Wo + (size_t)i * DD * DD;
        // pv partials (32 splits): chunk-combined ctx @ Wv
        k_gemv<3><<<512, 512, 0, stream>>>(nullptr, nullptr, ctx16, m_p, s_p,
                Wv_i, pvp);
        // o partials (32 splits): (sum pv + bv) @ Wo
        k_gemv<2><<<512, 512, 0, stream>>>(pvp, bv + i * DD, nullptr, nullptr,
                nullptr, Wo_i, op);
        if (i == NL - 1) {
            k_statsF<<<32, 1024, 0, stream>>>(op, bo + i * DD, gamma + i * DD,
                    beta + i * DD, out);
        } else {
            // fused: combine + LN + @Wq_{i+1} + bq -> qh rows
            k_qnext<<<256, 512, 0, stream>>>(op, bo + i * DD, gamma + i * DD,
                    beta + i * DD, Wq + (size_t)(i + 1) * DD * DD,
                    bq + (i + 1) * DD, qh);
            k_wk<0><<<256, 256, 0, stream>>>(qh, Wk + (size_t)(i + 1) * DD * DD,
                    bk + (i + 1) * DD, wk16, sbuf);
        }
    }
}

// Round 16
// 339.797 us; speedup vs baseline: 1.0282x; 1.0282x over previous
//
#include <hip/hip_runtime.h>
#include <hip/hip_bf16.h>
#include <cstdint>
#include <cstddef>

#define BB 32
#define LL 2048
#define DD 1024
#define HH 16
#define HDIM 64
#define NL 4
#define NCHUNK 16      // chunks per sequence
#define CHUNK 128      // tokens per chunk (grid 512 -> 2 blocks/CU co-resident)
#define NEGINF -1e30f
#define PKS 16         // K-splits for epilogue GEMV partials

typedef __attribute__((ext_vector_type(8))) short bf16x8;
typedef __attribute__((ext_vector_type(4))) float f32x4;

__device__ __forceinline__ unsigned short f2b(float x) {
    union { float f; unsigned int u; } v; v.f = x;
    unsigned int r = (v.u + 0x7FFFu + ((v.u >> 16) & 1u)) >> 16;
    return (unsigned short)r;
}
__device__ __forceinline__ float b2f(unsigned short u) {
    union { unsigned int u; float f; } v; v.u = ((unsigned int)u) << 16;
    return v.f;
}

// ---------------- split-K GEMV partials: part[ks][b][c] = X[b, e0:e0+64] @ W[e0:e0+64, c]
// SRC 2: X = bias + sum_{j2<PKS} parts_in    (combine pv partials)
// SRC 3: X = sum_c8 wgt[b][c8]*ctx16[...]    (softmax chunk combine; head = ct)
template<int SRC>
__global__ __launch_bounds__(512) void k_gemv(
        const float* __restrict__ parts_in, const float* __restrict__ bias_in,
        const unsigned short* __restrict__ ctx16, const float* __restrict__ m_p,
        const float* __restrict__ s_p,
        const float* __restrict__ W, float* __restrict__ outp) {
    constexpr int KL = DD / PKS;   // 64
    int bid = blockIdx.x, tid = threadIdx.x;
    int ct = bid & 15, ks = bid >> 4;
    int e0 = ks * KL;
    __shared__ float Xs[BB][KL];
    __shared__ float wgtS[BB][NCHUNK];
    __shared__ float mgS[BB], SgS[BB];
    if (SRC == 3) {
        if (tid < BB) {
            int b = tid; float m = NEGINF;
            for (int c8 = 0; c8 < NCHUNK; ++c8)
                m = fmaxf(m, m_p[(b * NCHUNK + c8) * HH + ct]);
            float S = 0.f;
            for (int c8 = 0; c8 < NCHUNK; ++c8)
                S += s_p[(b * NCHUNK + c8) * HH + ct] *
                     __expf(m_p[(b * NCHUNK + c8) * HH + ct] - m);
            mgS[b] = m; SgS[b] = S;
        }
        __syncthreads();
        {
            int b = tid >> 4, c8 = tid & 15;   // 512 threads = 32 x 16
            wgtS[b][c8] = __expf(m_p[(b * NCHUNK + c8) * HH + ct] - mgS[b]) / SgS[b];
        }
        __syncthreads();
    }
    // stage Xs[32][64]: thread = (b, kq of 4 elems), vectorized loads
    {
        int b = tid >> 4, kq = tid & 15;
        int k = kq * 4;
        float x0, x1, x2, x3;
        if (SRC == 2) {
            const float4 bi = *(const float4*)&bias_in[e0 + k];
            x0 = bi.x; x1 = bi.y; x2 = bi.z; x3 = bi.w;
#pragma unroll
            for (int j2 = 0; j2 < PKS; ++j2) {
                const float4 v = *(const float4*)&parts_in[((size_t)(j2 * BB) + b) * DD + e0 + k];
                x0 += v.x; x1 += v.y; x2 += v.z; x3 += v.w;
            }
        } else {
            x0 = x1 = x2 = x3 = 0.f;
            for (int c8 = 0; c8 < NCHUNK; ++c8) {
                float wq = wgtS[b][c8];
                if (wq == 0.f) continue;   // inactive chunk: exact-zero weight, skip load
                const ushort4 u = *(const ushort4*)&ctx16[(((size_t)(b * NCHUNK + c8)) * HH + ct) * DD + e0 + k];
                x0 += wq * b2f(u.x); x1 += wq * b2f(u.y);
                x2 += wq * b2f(u.z); x3 += wq * b2f(u.w);
            }
        }
        float4 xv = {x0, x1, x2, x3};
        *(float4*)&Xs[b][k] = xv;
    }
    __syncthreads();
    int col = tid & 63, bg = tid >> 6;   // bg 0..7, 4 b's each
    int c = ct * 64 + col;
    float acc[4] = {0.f, 0.f, 0.f, 0.f};
    for (int k = 0; k < KL; k += 4) {
        float w0 = W[(size_t)(e0 + k) * DD + c];
        float w1 = W[(size_t)(e0 + k + 1) * DD + c];
        float w2 = W[(size_t)(e0 + k + 2) * DD + c];
        float w3 = W[(size_t)(e0 + k + 3) * DD + c];
#pragma unroll
        for (int bb = 0; bb < 4; ++bb) {
            const float4 xv = *(const float4*)&Xs[bg * 4 + bb][k];
            acc[bb] += xv.x * w0 + xv.y * w1 + xv.z * w2 + xv.w * w3;
        }
    }
#pragma unroll
    for (int bb = 0; bb < 4; ++bb)
        outp[((size_t)(ks * BB) + bg * 4 + bb) * DD + c] = acc[bb];
}

// ---------------- last layer: combine op partials + bo + LN -> out (32 x 1024)
__global__ __launch_bounds__(1024) void k_statsF(const float* __restrict__ parts,
        const float* __restrict__ bo, const float* __restrict__ gamma,
        const float* __restrict__ beta, float* __restrict__ outp) {
    int b = blockIdx.x, c = threadIdx.x;
    float v = bo[c];
#pragma unroll
    for (int ks = 0; ks < PKS; ++ks)
        v += parts[((size_t)(ks * BB) + b) * DD + c];
    float s1 = v, s2 = v * v;
#pragma unroll
    for (int off = 32; off; off >>= 1) {
        s1 += __shfl_xor(s1, off);
        s2 += __shfl_xor(s2, off);
    }
    __shared__ float r1[16], r2[16];
    __shared__ float smu, srs;
    int w = c >> 6;
    if ((c & 63) == 0) { r1[w] = s1; r2[w] = s2; }
    __syncthreads();
    if (c == 0) {
        float a = 0.f, q = 0.f;
#pragma unroll
        for (int i = 0; i < 16; ++i) { a += r1[i]; q += r2[i]; }
        float mu = a / (float)DD, var = q / (float)DD - mu * mu;
        smu = mu; srs = rsqrtf(var + 1e-5f);
    }
    __syncthreads();
    outp[(size_t)b * DD + c] = (v - smu) * srs * gamma[c] + beta[c];
}

// ---------------- fused: op-combine + bo -> LN -> @Wq + bq -> qh rows
__global__ __launch_bounds__(512) void k_qnext(const float* __restrict__ op,
        const float* __restrict__ bo, const float* __restrict__ gamma,
        const float* __restrict__ beta, const float* __restrict__ Wq,
        const float* __restrict__ bq, float* __restrict__ qh) {
    int bid = blockIdx.x, tid = threadIdx.x;
    int ct = bid & 15, bp = bid >> 4;
    int b0 = bp * 2;
    __shared__ float Xr[2][DD];
    __shared__ float pr[8][2][64];
    __shared__ float r1[8], r2[8];
    __shared__ float smu[2], srs[2];
    {
        int bb = tid >> 8, c4 = tid & 255;
        int c = c4 * 4;
        float4 x = *(const float4*)&bo[c];
#pragma unroll
        for (int ks = 0; ks < PKS; ++ks) {
            const float4 v = *(const float4*)&op[((size_t)(ks * BB) + b0 + bb) * DD + c];
            x.x += v.x; x.y += v.y; x.z += v.z; x.w += v.w;
        }
        *(float4*)&Xr[bb][c] = x;
    }
    __syncthreads();
    {
        int bb = tid >> 8, l = tid & 255;
        const float4 x = *(const float4*)&Xr[bb][l * 4];
        float s1 = x.x + x.y + x.z + x.w;
        float s2 = x.x * x.x + x.y * x.y + x.z * x.z + x.w * x.w;
#pragma unroll
        for (int off = 32; off; off >>= 1) {
            s1 += __shfl_xor(s1, off);
            s2 += __shfl_xor(s2, off);
        }
        int w = tid >> 6;
        if ((tid & 63) == 0) { r1[w] = s1; r2[w] = s2; }
    }
    __syncthreads();
    if (tid < 2) {
        float a = r1[tid * 4] + r1[tid * 4 + 1] + r1[tid * 4 + 2] + r1[tid * 4 + 3];
        float q = r2[tid * 4] + r2[tid * 4 + 1] + r2[tid * 4 + 2] + r2[tid * 4 + 3];
        float mu = a / (float)DD, var = q / (float)DD - mu * mu;
        smu[tid] = mu; srs[tid] = rsqrtf(var + 1e-5f);
    }
    __syncthreads();
    {
        int c = tid & 63, ks8 = tid >> 6;
        float mu0 = smu[0], rs0 = srs[0], mu1 = smu[1], rs1 = srs[1];
        float acc0 = 0.f, acc1 = 0.f;
        int k0 = ks8 * 128;
        for (int k = k0; k < k0 + 128; ++k) {
            float g = gamma[k], be = beta[k];
            float w = Wq[(size_t)k * DD + ct * 64 + c];
            float x0 = (Xr[0][k] - mu0) * rs0 * g + be;
            float x1 = (Xr[1][k] - mu1) * rs1 * g + be;
            acc0 += x0 * w;
            acc1 += x1 * w;
        }
        pr[ks8][0][c] = acc0;
        pr[ks8][1][c] = acc1;
    }
    __syncthreads();
    if (tid < 128) {
        int bb = tid >> 6, c = tid & 63;
        float q = bq[ct * 64 + c];
#pragma unroll
        for (int j = 0; j < 8; ++j) q += pr[j][bb][c];
        qh[((size_t)(b0 + bb)) * DD + ct * 64 + c] = q;
    }
}

// ---------------- prologue: qh[0] = qt @ Wq0 + bq0 (one row; all b identical)
__global__ __launch_bounds__(256) void k_q0(const float* __restrict__ qt,
        const float* __restrict__ Wq, const float* __restrict__ bq,
        float* __restrict__ qh) {
    int ct = blockIdx.x, tid = threadIdx.x;
    __shared__ float pr[4][64];
    int c = tid & 63, ks4 = tid >> 6;
    float acc = 0.f;
    int k0 = ks4 * 256;
    for (int k = k0; k < k0 + 256; ++k)
        acc += qt[k] * Wq[(size_t)k * DD + ct * 64 + c];
    pr[ks4][c] = acc;
    __syncthreads();
    if (tid < 64) {
        float q = bq[ct * 64 + tid];
#pragma unroll
        for (int j = 0; j < 4; ++j) q += pr[j][tid];
        qh[ct * 64 + tid] = q;
    }
}

// ---------------- wk[b,h,e] = Wk[e, h*64:+64] . qh[b|0, h*64:+64] (bf16) + sbuf
template<int BCAST>
__global__ __launch_bounds__(256) void k_wk(const float* __restrict__ qh,
        const float* __restrict__ Wk, const float* __restrict__ bk,
        unsigned short* __restrict__ wk16, float* __restrict__ sb) {
    int h = blockIdx.x >> 4, et = blockIdx.x & 15;
    int tid = threadIdx.x;
    __shared__ float qs[BB][HDIM + 1];
    for (int i = tid; i < BB * HDIM; i += 256) {
        int bb = i >> 6, d = i & 63;
        qs[bb][d] = qh[((size_t)(BCAST ? 0 : bb)) * DD + h * HDIM + d];
    }
    __syncthreads();
    int b = tid & 31, eo = tid >> 5;   // eo: 0..7
    for (int k = 0; k < 8; ++k) {
        int e = et * 64 + eo * 8 + k;
        const float* wrow = Wk + (size_t)e * DD + h * HDIM;
        float acc = 0.f;
#pragma unroll
        for (int d = 0; d < HDIM; ++d) acc += qs[b][d] * wrow[d];
        wk16[((size_t)(b * HH + h)) * DD + e] = f2b(acc);
    }
    if (et == 0 && tid < BB) {
        float acc = 0.f;
#pragma unroll
        for (int d = 0; d < HDIM; ++d) acc += qs[tid][d] * bk[h * HDIM + d];
        sb[tid * HH + h] = acc;
    }
}

// ---------------- main streaming attention pass (partial per (b, chunk)) — R14
// CHUNK=128, grid 512 -> 2 blocks/CU (76 KB LDS, 8 waves, <=128 VGPR).
// MODE 0: fp32 reads. MODE 1: fp32 reads + bf16 cache write. MODE 2: bf16 cache reads.
template<int MODE>
__global__ __launch_bounds__(512, 4) void k_attn(const float* __restrict__ toks,
        unsigned short* __restrict__ tcache,
        const int* __restrict__ lens, const unsigned short* __restrict__ wk16,
        const float* __restrict__ sb, unsigned short* __restrict__ ctx16,
        float* __restrict__ m_p, float* __restrict__ s_p) {
    int b = blockIdx.x >> 4, chunk = blockIdx.x & 15;
    int tid = threadIdx.x, lane = tid & 63, w = tid >> 6;   // w: 0..7
    int len = lens[b];
    int base = chunk * CHUNK;
    int pidx = (b * NCHUNK + chunk) * HH;
    if (base >= len) {
        if (tid < HH) { m_p[pidx + tid] = NEGINF; s_p[pidx + tid] = 0.f; }
        return;
    }
    int nv = min(CHUNK, len - base);
    int ng = (nv + 31) >> 5;

    __shared__ __align__(16) unsigned short Tr[32][1032];   // [t][e] bf16, 66.0 KB
    __shared__ unsigned short SredH[8][HH][34];             // bf16 partials, 8.7 KB
    __shared__ unsigned short Pt[HH][40];
    __shared__ float sm_m[HH], sm_s[HH], sm_c[HH];

    if (tid < HH) { sm_m[tid] = NEGINF; sm_s[tid] = 0.f; }

    int hq = lane & 15, qg = lane >> 4;
    const unsigned short* wkb = wk16 + ((size_t)(b * HH + hq)) * DD + w * 128 + 8 * qg;
    bf16x8 afr0 = *(const bf16x8*)(wkb);
    bf16x8 afr1 = *(const bf16x8*)(wkb + 32);
    bf16x8 afr2 = *(const bf16x8*)(wkb + 64);
    bf16x8 afr3 = *(const bf16x8*)(wkb + 96);
    f32x4 zer = {0.f, 0.f, 0.f, 0.f};
    f32x4 ctxacc[8] = {zer, zer, zer, zer, zer, zer, zer, zer};
    float sbh = sb[b * HH + (tid >> 5)];
    int st = tid >> 6;           // staging token = wave id (0..7)
    int se = lane * 16;          // staging e offset
    const size_t rowbase = (size_t)(b * LL + base);
    __syncthreads();

    for (int g = 0; g < ng; ++g) {
        int t0 = g * 32;
        if (MODE == 2) {
            const unsigned short* s0p = tcache + (rowbase + t0) * DD + se;
#pragma unroll
            for (int p = 0; p < 4; ++p) {
                const unsigned short* sp = s0p + (size_t)(p * 8 + st) * DD;
                *(bf16x8*)&Tr[p * 8 + st][se]     = *(const bf16x8*)sp;
                *(bf16x8*)&Tr[p * 8 + st][se + 8] = *(const bf16x8*)(sp + 8);
            }
        } else {
            const float* s0p = toks + (rowbase + t0) * DD + se;
#pragma unroll
            for (int p = 0; p < 4; ++p) {
                const float* sp = s0p + (size_t)(p * 8 + st) * DD;
                float4 a0 = *(const float4*)sp;
                float4 a1 = *(const float4*)(sp + 4);
                float4 a2 = *(const float4*)(sp + 8);
                float4 a3 = *(const float4*)(sp + 12);
                bf16x8 v0, v1;
                v0[0] = f2b(a0.x); v0[1] = f2b(a0.y); v0[2] = f2b(a0.z); v0[3] = f2b(a0.w);
                v0[4] = f2b(a1.x); v0[5] = f2b(a1.y); v0[6] = f2b(a1.z); v0[7] = f2b(a1.w);
                v1[0] = f2b(a2.x); v1[1] = f2b(a2.y); v1[2] = f2b(a2.z); v1[3] = f2b(a2.w);
                v1[4] = f2b(a3.x); v1[5] = f2b(a3.y); v1[6] = f2b(a3.z); v1[7] = f2b(a3.w);
                *(bf16x8*)&Tr[p * 8 + st][se]     = v0;
                *(bf16x8*)&Tr[p * 8 + st][se + 8] = v1;
                if (MODE == 1) {
                    unsigned short* cp = tcache + (rowbase + t0 + p * 8 + st) * DD + se;
                    *(bf16x8*)cp = v0;
                    *(bf16x8*)(cp + 8) = v1;
                }
            }
        }
        __syncthreads();
        f32x4 s0 = zer, s1 = zer;
        {
            int eb = w * 128 + 8 * qg;
            s0 = __builtin_amdgcn_mfma_f32_16x16x32_bf16(afr0, *(const bf16x8*)&Tr[hq][eb], s0, 0, 0, 0);
            s0 = __builtin_amdgcn_mfma_f32_16x16x32_bf16(afr1, *(const bf16x8*)&Tr[hq][eb + 32], s0, 0, 0, 0);
            s0 = __builtin_amdgcn_mfma_f32_16x16x32_bf16(afr2, *(const bf16x8*)&Tr[hq][eb + 64], s0, 0, 0, 0);
            s0 = __builtin_amdgcn_mfma_f32_16x16x32_bf16(afr3, *(const bf16x8*)&Tr[hq][eb + 96], s0, 0, 0, 0);
            s1 = __builtin_amdgcn_mfma_f32_16x16x32_bf16(afr0, *(const bf16x8*)&Tr[16 + hq][eb], s1, 0, 0, 0);
            s1 = __builtin_amdgcn_mfma_f32_16x16x32_bf16(afr1, *(const bf16x8*)&Tr[16 + hq][eb + 32], s1, 0, 0, 0);
            s1 = __builtin_amdgcn_mfma_f32_16x16x32_bf16(afr2, *(const bf16x8*)&Tr[16 + hq][eb + 64], s1, 0, 0, 0);
            s1 = __builtin_amdgcn_mfma_f32_16x16x32_bf16(afr3, *(const bf16x8*)&Tr[16 + hq][eb + 96], s1, 0, 0, 0);
        }
#pragma unroll
        for (int r = 0; r < 4; ++r) {
            SredH[w][qg * 4 + r][hq] = f2b(s0[r]);
            SredH[w][qg * 4 + r][16 + hq] = f2b(s1[r]);
        }
        __syncthreads();
        {
            int h = tid >> 5, t = tid & 31;
            float s = 0.f;
#pragma unroll
            for (int ww = 0; ww < 8; ++ww) s += b2f(SredH[ww][h][t]);
            s = (s + sbh) * 0.125f;
            bool valid = (t0 + t) < nv;
            if (!valid) s = NEGINF;
            float tm = s;
#pragma unroll
            for (int off = 16; off; off >>= 1) tm = fmaxf(tm, __shfl_xor(tm, off, 32));
            float oldm = sm_m[h];
            float newm = fmaxf(oldm, tm);
            float pv = valid ? __expf(s - newm) : 0.f;
            float ps = pv;
#pragma unroll
            for (int off = 16; off; off >>= 1) ps += __shfl_xor(ps, off, 32);
            if (t == 0) {
                float corr = __expf(oldm - newm);
                sm_c[h] = corr;
                sm_m[h] = newm;
                sm_s[h] = sm_s[h] * corr + ps;
            }
            Pt[h][t] = f2b(pv);
        }
        __syncthreads();
        {
            float cr[4];
#pragma unroll
            for (int r = 0; r < 4; ++r) cr[r] = sm_c[qg * 4 + r];
            bf16x8 pafr;
            ushort4 pa0 = *(const ushort4*)&Pt[hq][8 * qg];
            ushort4 pa1 = *(const ushort4*)&Pt[hq][8 * qg + 4];
            pafr[0] = pa0.x; pafr[1] = pa0.y; pafr[2] = pa0.z; pafr[3] = pa0.w;
            pafr[4] = pa1.x; pafr[5] = pa1.y; pafr[6] = pa1.z; pafr[7] = pa1.w;
#pragma unroll
            for (int et = 0; et < 8; ++et) {
#pragma unroll
                for (int r = 0; r < 4; ++r) ctxacc[et][r] *= cr[r];
                bf16x8 bfr;
                int ec = w * 128 + et * 16 + hq;
#pragma unroll
                for (int i = 0; i < 8; ++i) bfr[i] = (short)Tr[8 * qg + i][ec];
                ctxacc[et] = __builtin_amdgcn_mfma_f32_16x16x32_bf16(pafr, bfr, ctxacc[et], 0, 0, 0);
            }
        }
        __syncthreads();
    }
    if (tid < HH) { m_p[pidx + tid] = sm_m[tid]; s_p[pidx + tid] = sm_s[tid]; }
#pragma unroll
    for (int et = 0; et < 8; ++et)
#pragma unroll
        for (int r = 0; r < 4; ++r) {
            int h = qg * 4 + r, e = w * 128 + et * 16 + hq;
            ctx16[((size_t)pidx + h) * DD + e] = f2b(ctxacc[et][r]);
        }
}

extern "C" void kernel_launch(void* const* d_in, const int* in_sizes, int n_in,
                              void* d_out, int out_size, void* d_ws, size_t ws_size,
                              hipStream_t stream) {
    const float* toks  = (const float*)d_in[0];
    const int*   lens  = (const int*)d_in[1];
    const float* qt    = (const float*)d_in[2];
    const float* Wq    = (const float*)d_in[3];
    const float* bq    = (const float*)d_in[4];
    const float* Wk    = (const float*)d_in[5];
    const float* bk    = (const float*)d_in[6];
    const float* Wv    = (const float*)d_in[7];
    const float* bv    = (const float*)d_in[8];
    const float* Wo    = (const float*)d_in[9];
    const float* bo    = (const float*)d_in[10];
    const float* gamma = (const float*)d_in[11];
    const float* beta  = (const float*)d_in[12];
    float* out = (float*)d_out;
    float* ws  = (float*)d_ws;

    // ws layout (float offsets) — R14 layout
    unsigned short* ctx16 = (unsigned short*)ws;   // 32*16*16*1024 u16 = 4194304 f
    float* m_p   = ws + 4194304;             // 8192
    float* s_p   = ws + 4202496;             // 8192
    float* pvp   = ws + 4210688;             // 524288 (16 partials)
    float* op    = ws + 4734976;             // 524288
    float* qh    = ws + 5259264;             // 32768
    float* sbuf  = ws + 5292032;             // 512
    unsigned short* wk16 = (unsigned short*)(ws + 5292544);  // 524288 u16
    const size_t base_floats = 5554688;
    unsigned short* tcache = (unsigned short*)(ws + base_floats);
    const size_t need_cache = base_floats * 4 + (size_t)BB * LL * DD * 2;
    const bool use_cache = (ws_size >= need_cache);

    // prologue: qh row 0 = qt @ Wq0 + bq0; wk layer 0 writes ALL rows
    k_q0<<<16, 256, 0, stream>>>(qt, Wq, bq, qh);
    k_wk<1><<<256, 256, 0, stream>>>(qh, Wk, bk, wk16, sbuf);

    for (int i = 0; i < NL; ++i) {
        if (use_cache) {
            if (i == 0)
                k_attn<1><<<512, 512, 0, stream>>>(toks, tcache, lens, wk16,
                        sbuf, ctx16, m_p, s_p);
            else
                k_attn<2><<<512, 512, 0, stream>>>(toks, tcache, lens, wk16,
                        sbuf, ctx16, m_p, s_p);
        } else {
            k_attn<0><<<512, 512, 0, stream>>>(toks, tcache, lens, wk16,
                    sbuf, ctx16, m_p, s_p);
        }
        const float* Wv_i = Wv + (size_t)i * DD * DD;
        const float* Wo_i = Wo + (size_t)i * DD * DD;
        // pv partials: chunk-combined ctx @ Wv (skips zero-weight chunks)
        k_gemv<3><<<256, 512, 0, stream>>>(nullptr, nullptr, ctx16, m_p, s_p,
                Wv_i, pvp);
        // o partials: (sum pv + bv) @ Wo
        k_gemv<2><<<256, 512, 0, stream>>>(pvp, bv + i * DD, nullptr, nullptr,
                nullptr, Wo_i, op);
        if (i == NL - 1) {
            k_statsF<<<32, 1024, 0, stream>>>(op, bo + i * DD, gamma + i * DD,
                    beta + i * DD, out);
        } else {
            // fused: combine + LN + @Wq_{i+1} + bq -> qh rows
            k_qnext<<<256, 512, 0, stream>>>(op, bo + i * DD, gamma + i * DD,
                    beta + i * DD, Wq + (size_t)(i + 1) * DD * DD,
                    bq + (i + 1) * DD, qh);
            k_wk<0><<<256, 256, 0, stream>>>(qh, Wk + (size_t)(i + 1) * DD * DD,
                    bk + (i + 1) * DD, wk16, sbuf);
        }
    }
}

// Round 17
// 329.685 us; speedup vs baseline: 1.0597x; 1.0307x over previous
//
#include <hip/hip_runtime.h>
#include <hip/hip_bf16.h>
#include <cstdint>
#include <cstddef>

#define BB 32
#define LL 2048
#define DD 1024
#define HH 16
#define HDIM 64
#define NL 4
#define NCHUNK 16      // chunks per sequence
#define CHUNK 128      // tokens per chunk (grid 512 -> 2 blocks/CU co-resident)
#define NEGINF -1e30f
#define PKS 16         // K-splits for epilogue GEMV partials

typedef __attribute__((ext_vector_type(8))) short bf16x8;
typedef __attribute__((ext_vector_type(4))) float f32x4;

__device__ __forceinline__ unsigned short f2b(float x) {
    union { float f; unsigned int u; } v; v.f = x;
    unsigned int r = (v.u + 0x7FFFu + ((v.u >> 16) & 1u)) >> 16;
    return (unsigned short)r;
}
__device__ __forceinline__ float b2f(unsigned short u) {
    union { unsigned int u; float f; } v; v.u = ((unsigned int)u) << 16;
    return v.f;
}

// ---------------- split-K GEMV partials: part[ks][b][c] = X[b, e0:e0+64] @ W[e0:e0+64, c]
// SRC 2: X = bias + sum_{j2<PKS} parts_in    (combine pv partials)
// SRC 3: X = sum_c8 wgt[b][c8]*ctx16[...]    (softmax chunk combine; head = ct)
template<int SRC>
__global__ __launch_bounds__(512) void k_gemv(
        const float* __restrict__ parts_in, const float* __restrict__ bias_in,
        const unsigned short* __restrict__ ctx16, const float* __restrict__ m_p,
        const float* __restrict__ s_p,
        const float* __restrict__ W, float* __restrict__ outp) {
    constexpr int KL = DD / PKS;   // 64
    int bid = blockIdx.x, tid = threadIdx.x;
    int ct = bid & 15, ks = bid >> 4;
    int e0 = ks * KL;
    __shared__ float Xs[BB][KL];
    __shared__ float wgtS[BB][NCHUNK];
    __shared__ float mgS[BB], SgS[BB];
    if (SRC == 3) {
        if (tid < BB) {
            int b = tid; float m = NEGINF;
            for (int c8 = 0; c8 < NCHUNK; ++c8)
                m = fmaxf(m, m_p[(b * NCHUNK + c8) * HH + ct]);
            float S = 0.f;
            for (int c8 = 0; c8 < NCHUNK; ++c8)
                S += s_p[(b * NCHUNK + c8) * HH + ct] *
                     __expf(m_p[(b * NCHUNK + c8) * HH + ct] - m);
            mgS[b] = m; SgS[b] = S;
        }
        __syncthreads();
        {
            int b = tid >> 4, c8 = tid & 15;   // 512 threads = 32 x 16
            wgtS[b][c8] = __expf(m_p[(b * NCHUNK + c8) * HH + ct] - mgS[b]) / SgS[b];
        }
        __syncthreads();
    }
    // stage Xs[32][64]: thread = (b, kq of 4 elems), vectorized loads
    {
        int b = tid >> 4, kq = tid & 15;
        int k = kq * 4;
        float x0, x1, x2, x3;
        if (SRC == 2) {
            const float4 bi = *(const float4*)&bias_in[e0 + k];
            x0 = bi.x; x1 = bi.y; x2 = bi.z; x3 = bi.w;
#pragma unroll
            for (int j2 = 0; j2 < PKS; ++j2) {
                const float4 v = *(const float4*)&parts_in[((size_t)(j2 * BB) + b) * DD + e0 + k];
                x0 += v.x; x1 += v.y; x2 += v.z; x3 += v.w;
            }
        } else {
            x0 = x1 = x2 = x3 = 0.f;
#pragma unroll
            for (int c8 = 0; c8 < NCHUNK; ++c8) {
                const ushort4 u = *(const ushort4*)&ctx16[(((size_t)(b * NCHUNK + c8)) * HH + ct) * DD + e0 + k];
                float wq = wgtS[b][c8];
                x0 += wq * b2f(u.x); x1 += wq * b2f(u.y);
                x2 += wq * b2f(u.z); x3 += wq * b2f(u.w);
            }
        }
        float4 xv = {x0, x1, x2, x3};
        *(float4*)&Xs[b][k] = xv;
    }
    __syncthreads();
    int col = tid & 63, bg = tid >> 6;   // bg 0..7, 4 b's each
    int c = ct * 64 + col;
    float acc[4] = {0.f, 0.f, 0.f, 0.f};
    for (int k = 0; k < KL; k += 4) {
        float w0 = W[(size_t)(e0 + k) * DD + c];
        float w1 = W[(size_t)(e0 + k + 1) * DD + c];
        float w2 = W[(size_t)(e0 + k + 2) * DD + c];
        float w3 = W[(size_t)(e0 + k + 3) * DD + c];
#pragma unroll
        for (int bb = 0; bb < 4; ++bb) {
            const float4 xv = *(const float4*)&Xs[bg * 4 + bb][k];
            acc[bb] += xv.x * w0 + xv.y * w1 + xv.z * w2 + xv.w * w3;
        }
    }
#pragma unroll
    for (int bb = 0; bb < 4; ++bb)
        outp[((size_t)(ks * BB) + bg * 4 + bb) * DD + c] = acc[bb];
}

// ---------------- last layer: combine op partials + bo + LN -> out (32 x 1024)
__global__ __launch_bounds__(1024) void k_statsF(const float* __restrict__ parts,
        const float* __restrict__ bo, const float* __restrict__ gamma,
        const float* __restrict__ beta, float* __restrict__ outp) {
    int b = blockIdx.x, c = threadIdx.x;
    float v = bo[c];
#pragma unroll
    for (int ks = 0; ks < PKS; ++ks)
        v += parts[((size_t)(ks * BB) + b) * DD + c];
    float s1 = v, s2 = v * v;
#pragma unroll
    for (int off = 32; off; off >>= 1) {
        s1 += __shfl_xor(s1, off);
        s2 += __shfl_xor(s2, off);
    }
    __shared__ float r1[16], r2[16];
    __shared__ float smu, srs;
    int w = c >> 6;
    if ((c & 63) == 0) { r1[w] = s1; r2[w] = s2; }
    __syncthreads();
    if (c == 0) {
        float a = 0.f, q = 0.f;
#pragma unroll
        for (int i = 0; i < 16; ++i) { a += r1[i]; q += r2[i]; }
        float mu = a / (float)DD, var = q / (float)DD - mu * mu;
        smu = mu; srs = rsqrtf(var + 1e-5f);
    }
    __syncthreads();
    outp[(size_t)b * DD + c] = (v - smu) * srs * gamma[c] + beta[c];
}

// ---------------- fused: op-combine + bo -> LN -> @Wq + bq -> qh rows
__global__ __launch_bounds__(512) void k_qnext(const float* __restrict__ op,
        const float* __restrict__ bo, const float* __restrict__ gamma,
        const float* __restrict__ beta, const float* __restrict__ Wq,
        const float* __restrict__ bq, float* __restrict__ qh) {
    int bid = blockIdx.x, tid = threadIdx.x;
    int ct = bid & 15, bp = bid >> 4;
    int b0 = bp * 2;
    __shared__ float Xr[2][DD];
    __shared__ float pr[8][2][64];
    __shared__ float r1[8], r2[8];
    __shared__ float smu[2], srs[2];
    {
        int bb = tid >> 8, c4 = tid & 255;
        int c = c4 * 4;
        float4 x = *(const float4*)&bo[c];
#pragma unroll
        for (int ks = 0; ks < PKS; ++ks) {
            const float4 v = *(const float4*)&op[((size_t)(ks * BB) + b0 + bb) * DD + c];
            x.x += v.x; x.y += v.y; x.z += v.z; x.w += v.w;
        }
        *(float4*)&Xr[bb][c] = x;
    }
    __syncthreads();
    {
        int bb = tid >> 8, l = tid & 255;
        const float4 x = *(const float4*)&Xr[bb][l * 4];
        float s1 = x.x + x.y + x.z + x.w;
        float s2 = x.x * x.x + x.y * x.y + x.z * x.z + x.w * x.w;
#pragma unroll
        for (int off = 32; off; off >>= 1) {
            s1 += __shfl_xor(s1, off);
            s2 += __shfl_xor(s2, off);
        }
        int w = tid >> 6;
        if ((tid & 63) == 0) { r1[w] = s1; r2[w] = s2; }
    }
    __syncthreads();
    if (tid < 2) {
        float a = r1[tid * 4] + r1[tid * 4 + 1] + r1[tid * 4 + 2] + r1[tid * 4 + 3];
        float q = r2[tid * 4] + r2[tid * 4 + 1] + r2[tid * 4 + 2] + r2[tid * 4 + 3];
        float mu = a / (float)DD, var = q / (float)DD - mu * mu;
        smu[tid] = mu; srs[tid] = rsqrtf(var + 1e-5f);
    }
    __syncthreads();
    {
        int c = tid & 63, ks8 = tid >> 6;
        float mu0 = smu[0], rs0 = srs[0], mu1 = smu[1], rs1 = srs[1];
        float acc0 = 0.f, acc1 = 0.f;
        int k0 = ks8 * 128;
        for (int k = k0; k < k0 + 128; ++k) {
            float g = gamma[k], be = beta[k];
            float w = Wq[(size_t)k * DD + ct * 64 + c];
            float x0 = (Xr[0][k] - mu0) * rs0 * g + be;
            float x1 = (Xr[1][k] - mu1) * rs1 * g + be;
            acc0 += x0 * w;
            acc1 += x1 * w;
        }
        pr[ks8][0][c] = acc0;
        pr[ks8][1][c] = acc1;
    }
    __syncthreads();
    if (tid < 128) {
        int bb = tid >> 6, c = tid & 63;
        float q = bq[ct * 64 + c];
#pragma unroll
        for (int j = 0; j < 8; ++j) q += pr[j][bb][c];
        qh[((size_t)(b0 + bb)) * DD + ct * 64 + c] = q;
    }
}

// ---------------- prologue: qh[0] = qt @ Wq0 + bq0 (one row; all b identical)
__global__ __launch_bounds__(256) void k_q0(const float* __restrict__ qt,
        const float* __restrict__ Wq, const float* __restrict__ bq,
        float* __restrict__ qh) {
    int ct = blockIdx.x, tid = threadIdx.x;
    __shared__ float pr[4][64];
    int c = tid & 63, ks4 = tid >> 6;
    float acc = 0.f;
    int k0 = ks4 * 256;
    for (int k = k0; k < k0 + 256; ++k)
        acc += qt[k] * Wq[(size_t)k * DD + ct * 64 + c];
    pr[ks4][c] = acc;
    __syncthreads();
    if (tid < 64) {
        float q = bq[ct * 64 + tid];
#pragma unroll
        for (int j = 0; j < 4; ++j) q += pr[j][tid];
        qh[ct * 64 + tid] = q;
    }
}

// ---------------- wk[b,h,e] = Wk[e, h*64:+64] . qh[b|0, h*64:+64] (bf16) + sbuf
template<int BCAST>
__global__ __launch_bounds__(256) void k_wk(const float* __restrict__ qh,
        const float* __restrict__ Wk, const float* __restrict__ bk,
        unsigned short* __restrict__ wk16, float* __restrict__ sb) {
    int h = blockIdx.x >> 4, et = blockIdx.x & 15;
    int tid = threadIdx.x;
    __shared__ float qs[BB][HDIM + 1];
    for (int i = tid; i < BB * HDIM; i += 256) {
        int bb = i >> 6, d = i & 63;
        qs[bb][d] = qh[((size_t)(BCAST ? 0 : bb)) * DD + h * HDIM + d];
    }
    __syncthreads();
    int b = tid & 31, eo = tid >> 5;   // eo: 0..7
    for (int k = 0; k < 8; ++k) {
        int e = et * 64 + eo * 8 + k;
        const float* wrow = Wk + (size_t)e * DD + h * HDIM;
        float acc = 0.f;
#pragma unroll
        for (int d = 0; d < HDIM; ++d) acc += qs[b][d] * wrow[d];
        wk16[((size_t)(b * HH + h)) * DD + e] = f2b(acc);
    }
    if (et == 0 && tid < BB) {
        float acc = 0.f;
#pragma unroll
        for (int d = 0; d < HDIM; ++d) acc += qs[tid][d] * bk[h * HDIM + d];
        sb[tid * HH + h] = acc;
    }
}

// ---------------- main streaming attention pass (partial per (b, chunk)) — R14
// CHUNK=128, grid 512 -> 2 blocks/CU (76 KB LDS, 8 waves, <=128 VGPR).
// MODE 0: fp32 reads. MODE 1: fp32 reads + bf16 cache write. MODE 2: bf16 cache reads.
template<int MODE>
__global__ __launch_bounds__(512, 4) void k_attn(const float* __restrict__ toks,
        unsigned short* __restrict__ tcache,
        const int* __restrict__ lens, const unsigned short* __restrict__ wk16,
        const float* __restrict__ sb, unsigned short* __restrict__ ctx16,
        float* __restrict__ m_p, float* __restrict__ s_p) {
    int b = blockIdx.x >> 4, chunk = blockIdx.x & 15;
    int tid = threadIdx.x, lane = tid & 63, w = tid >> 6;   // w: 0..7
    int len = lens[b];
    int base = chunk * CHUNK;
    int pidx = (b * NCHUNK + chunk) * HH;
    if (base >= len) {
        if (tid < HH) { m_p[pidx + tid] = NEGINF; s_p[pidx + tid] = 0.f; }
        return;
    }
    int nv = min(CHUNK, len - base);
    int ng = (nv + 31) >> 5;

    __shared__ __align__(16) unsigned short Tr[32][1032];   // [t][e] bf16, 66.0 KB
    __shared__ unsigned short SredH[8][HH][34];             // bf16 partials, 8.7 KB
    __shared__ unsigned short Pt[HH][40];
    __shared__ float sm_m[HH], sm_s[HH], sm_c[HH];

    if (tid < HH) { sm_m[tid] = NEGINF; sm_s[tid] = 0.f; }

    int hq = lane & 15, qg = lane >> 4;
    const unsigned short* wkb = wk16 + ((size_t)(b * HH + hq)) * DD + w * 128 + 8 * qg;
    bf16x8 afr0 = *(const bf16x8*)(wkb);
    bf16x8 afr1 = *(const bf16x8*)(wkb + 32);
    bf16x8 afr2 = *(const bf16x8*)(wkb + 64);
    bf16x8 afr3 = *(const bf16x8*)(wkb + 96);
    f32x4 zer = {0.f, 0.f, 0.f, 0.f};
    f32x4 ctxacc[8] = {zer, zer, zer, zer, zer, zer, zer, zer};
    float sbh = sb[b * HH + (tid >> 5)];
    int st = tid >> 6;           // staging token = wave id (0..7)
    int se = lane * 16;          // staging e offset
    const size_t rowbase = (size_t)(b * LL + base);
    __syncthreads();

    for (int g = 0; g < ng; ++g) {
        int t0 = g * 32;
        if (MODE == 2) {
            const unsigned short* s0p = tcache + (rowbase + t0) * DD + se;
#pragma unroll
            for (int p = 0; p < 4; ++p) {
                const unsigned short* sp = s0p + (size_t)(p * 8 + st) * DD;
                *(bf16x8*)&Tr[p * 8 + st][se]     = *(const bf16x8*)sp;
                *(bf16x8*)&Tr[p * 8 + st][se + 8] = *(const bf16x8*)(sp + 8);
            }
        } else {
            const float* s0p = toks + (rowbase + t0) * DD + se;
#pragma unroll
            for (int p = 0; p < 4; ++p) {
                const float* sp = s0p + (size_t)(p * 8 + st) * DD;
                float4 a0 = *(const float4*)sp;
                float4 a1 = *(const float4*)(sp + 4);
                float4 a2 = *(const float4*)(sp + 8);
                float4 a3 = *(const float4*)(sp + 12);
                bf16x8 v0, v1;
                v0[0] = f2b(a0.x); v0[1] = f2b(a0.y); v0[2] = f2b(a0.z); v0[3] = f2b(a0.w);
                v0[4] = f2b(a1.x); v0[5] = f2b(a1.y); v0[6] = f2b(a1.z); v0[7] = f2b(a1.w);
                v1[0] = f2b(a2.x); v1[1] = f2b(a2.y); v1[2] = f2b(a2.z); v1[3] = f2b(a2.w);
                v1[4] = f2b(a3.x); v1[5] = f2b(a3.y); v1[6] = f2b(a3.z); v1[7] = f2b(a3.w);
                *(bf16x8*)&Tr[p * 8 + st][se]     = v0;
                *(bf16x8*)&Tr[p * 8 + st][se + 8] = v1;
                if (MODE == 1) {
                    unsigned short* cp = tcache + (rowbase + t0 + p * 8 + st) * DD + se;
                    *(bf16x8*)cp = v0;
                    *(bf16x8*)(cp + 8) = v1;
                }
            }
        }
        __syncthreads();
        f32x4 s0 = zer, s1 = zer;
        {
            int eb = w * 128 + 8 * qg;
            s0 = __builtin_amdgcn_mfma_f32_16x16x32_bf16(afr0, *(const bf16x8*)&Tr[hq][eb], s0, 0, 0, 0);
            s0 = __builtin_amdgcn_mfma_f32_16x16x32_bf16(afr1, *(const bf16x8*)&Tr[hq][eb + 32], s0, 0, 0, 0);
            s0 = __builtin_amdgcn_mfma_f32_16x16x32_bf16(afr2, *(const bf16x8*)&Tr[hq][eb + 64], s0, 0, 0, 0);
            s0 = __builtin_amdgcn_mfma_f32_16x16x32_bf16(afr3, *(const bf16x8*)&Tr[hq][eb + 96], s0, 0, 0, 0);
            s1 = __builtin_amdgcn_mfma_f32_16x16x32_bf16(afr0, *(const bf16x8*)&Tr[16 + hq][eb], s1, 0, 0, 0);
            s1 = __builtin_amdgcn_mfma_f32_16x16x32_bf16(afr1, *(const bf16x8*)&Tr[16 + hq][eb + 32], s1, 0, 0, 0);
            s1 = __builtin_amdgcn_mfma_f32_16x16x32_bf16(afr2, *(const bf16x8*)&Tr[16 + hq][eb + 64], s1, 0, 0, 0);
            s1 = __builtin_amdgcn_mfma_f32_16x16x32_bf16(afr3, *(const bf16x8*)&Tr[16 + hq][eb + 96], s1, 0, 0, 0);
        }
#pragma unroll
        for (int r = 0; r < 4; ++r) {
            SredH[w][qg * 4 + r][hq] = f2b(s0[r]);
            SredH[w][qg * 4 + r][16 + hq] = f2b(s1[r]);
        }
        __syncthreads();
        {
            int h = tid >> 5, t = tid & 31;
            float s = 0.f;
#pragma unroll
            for (int ww = 0; ww < 8; ++ww) s += b2f(SredH[ww][h][t]);
            s = (s + sbh) * 0.125f;
            bool valid = (t0 + t) < nv;
            if (!valid) s = NEGINF;
            float tm = s;
#pragma unroll
            for (int off = 16; off; off >>= 1) tm = fmaxf(tm, __shfl_xor(tm, off, 32));
            float oldm = sm_m[h];
            float newm = fmaxf(oldm, tm);
            float pv = valid ? __expf(s - newm) : 0.f;
            float ps = pv;
#pragma unroll
            for (int off = 16; off; off >>= 1) ps += __shfl_xor(ps, off, 32);
            if (t == 0) {
                float corr = __expf(oldm - newm);
                sm_c[h] = corr;
                sm_m[h] = newm;
                sm_s[h] = sm_s[h] * corr + ps;
            }
            Pt[h][t] = f2b(pv);
        }
        __syncthreads();
        {
            float cr[4];
#pragma unroll
            for (int r = 0; r < 4; ++r) cr[r] = sm_c[qg * 4 + r];
            bf16x8 pafr;
            ushort4 pa0 = *(const ushort4*)&Pt[hq][8 * qg];
            ushort4 pa1 = *(const ushort4*)&Pt[hq][8 * qg + 4];
            pafr[0] = pa0.x; pafr[1] = pa0.y; pafr[2] = pa0.z; pafr[3] = pa0.w;
            pafr[4] = pa1.x; pafr[5] = pa1.y; pafr[6] = pa1.z; pafr[7] = pa1.w;
#pragma unroll
            for (int et = 0; et < 8; ++et) {
#pragma unroll
                for (int r = 0; r < 4; ++r) ctxacc[et][r] *= cr[r];
                bf16x8 bfr;
                int ec = w * 128 + et * 16 + hq;
#pragma unroll
                for (int i = 0; i < 8; ++i) bfr[i] = (short)Tr[8 * qg + i][ec];
                ctxacc[et] = __builtin_amdgcn_mfma_f32_16x16x32_bf16(pafr, bfr, ctxacc[et], 0, 0, 0);
            }
        }
        __syncthreads();
    }
    if (tid < HH) { m_p[pidx + tid] = sm_m[tid]; s_p[pidx + tid] = sm_s[tid]; }
#pragma unroll
    for (int et = 0; et < 8; ++et)
#pragma unroll
        for (int r = 0; r < 4; ++r) {
            int h = qg * 4 + r, e = w * 128 + et * 16 + hq;
            ctx16[((size_t)pidx + h) * DD + e] = f2b(ctxacc[et][r]);
        }
}

extern "C" void kernel_launch(void* const* d_in, const int* in_sizes, int n_in,
                              void* d_out, int out_size, void* d_ws, size_t ws_size,
                              hipStream_t stream) {
    const float* toks  = (const float*)d_in[0];
    const int*   lens  = (const int*)d_in[1];
    const float* qt    = (const float*)d_in[2];
    const float* Wq    = (const float*)d_in[3];
    const float* bq    = (const float*)d_in[4];
    const float* Wk    = (const float*)d_in[5];
    const float* bk    = (const float*)d_in[6];
    const float* Wv    = (const float*)d_in[7];
    const float* bv    = (const float*)d_in[8];
    const float* Wo    = (const float*)d_in[9];
    const float* bo    = (const float*)d_in[10];
    const float* gamma = (const float*)d_in[11];
    const float* beta  = (const float*)d_in[12];
    float* out = (float*)d_out;
    float* ws  = (float*)d_ws;

    // ws layout (float offsets) — R14 layout
    unsigned short* ctx16 = (unsigned short*)ws;   // 32*16*16*1024 u16 = 4194304 f
    float* m_p   = ws + 4194304;             // 8192
    float* s_p   = ws + 4202496;             // 8192
    float* pvp   = ws + 4210688;             // 524288 (16 partials)
    float* op    = ws + 4734976;             // 524288
    float* qh    = ws + 5259264;             // 32768
    float* sbuf  = ws + 5292032;             // 512
    unsigned short* wk16 = (unsigned short*)(ws + 5292544);  // 524288 u16
    const size_t base_floats = 5554688;
    unsigned short* tcache = (unsigned short*)(ws + base_floats);
    const size_t need_cache = base_floats * 4 + (size_t)BB * LL * DD * 2;
    const bool use_cache = (ws_size >= need_cache);

    // prologue: qh row 0 = qt @ Wq0 + bq0; wk layer 0 writes ALL rows
    k_q0<<<16, 256, 0, stream>>>(qt, Wq, bq, qh);
    k_wk<1><<<256, 256, 0, stream>>>(qh, Wk, bk, wk16, sbuf);

    for (int i = 0; i < NL; ++i) {
        if (use_cache) {
            if (i == 0)
                k_attn<1><<<512, 512, 0, stream>>>(toks, tcache, lens, wk16,
                        sbuf, ctx16, m_p, s_p);
            else
                k_attn<2><<<512, 512, 0, stream>>>(toks, tcache, lens, wk16,
                        sbuf, ctx16, m_p, s_p);
        } else {
            k_attn<0><<<512, 512, 0, stream>>>(toks, tcache, lens, wk16,
                    sbuf, ctx16, m_p, s_p);
        }
        const float* Wv_i = Wv + (size_t)i * DD * DD;
        const float* Wo_i = Wo + (size_t)i * DD * DD;
        // pv partials: chunk-combined ctx @ Wv
        k_gemv<3><<<256, 512, 0, stream>>>(nullptr, nullptr, ctx16, m_p, s_p,
                Wv_i, pvp);
        // o partials: (sum pv + bv) @ Wo
        k_gemv<2><<<256, 512, 0, stream>>>(pvp, bv + i * DD, nullptr, nullptr,
                nullptr, Wo_i, op);
        if (i == NL - 1) {
            k_statsF<<<32, 1024, 0, stream>>>(op, bo + i * DD, gamma + i * DD,
                    beta + i * DD, out);
        } else {
            // fused: combine + LN + @Wq_{i+1} + bq -> qh rows
            k_qnext<<<256, 512, 0, stream>>>(op, bo + i * DD, gamma + i * DD,
                    beta + i * DD, Wq + (size_t)(i + 1) * DD * DD,
                    bq + (i + 1) * DD, qh);
            k_wk<0><<<256, 256, 0, stream>>>(qh, Wk + (size_t)(i + 1) * DD * DD,
                    bk + (i + 1) * DD, wk16, sbuf);
        }
    }
}